// Round 12
// baseline (171.242 us; speedup 1.0000x reference)
//
#include <hip/hip_runtime.h>
#include <hip/hip_bf16.h>

#define NBATCH 4
#define NSEQ   1024
#define RD     256
#define NHEAD  8
#define HD     64
#define NHD    512   // NHEAD*HD

typedef __attribute__((ext_vector_type(8))) short  short8;
typedef __attribute__((ext_vector_type(4))) short  short4v;
typedef __attribute__((ext_vector_type(4))) float  float4v;

#define MFMA16(a,b,c) __builtin_amdgcn_mfma_f32_16x16x32_bf16(a,b,c,0,0,0)

typedef const void __attribute__((address_space(1)))* gas_t;
typedef void __attribute__((address_space(3)))* las_t;
#define GLOAD16(g, l) __builtin_amdgcn_global_load_lds((gas_t)(g), (las_t)(l), 16, 0, 0)

// Native bf16 cast (RNE, same bits as manual round) — compiler emits fast cvt.
static __device__ __forceinline__ short f2b(float f) {
    __hip_bfloat16 h = __float2bfloat16(f);
    union { __hip_bfloat16 h; short s; } u; u.h = h;
    return u.s;
}
static __device__ __forceinline__ void st4(short* dst, float4v v) {
    short4v p;
    p[0] = f2b(v[0]); p[1] = f2b(v[1]);
    p[2] = f2b(v[2]); p[3] = f2b(v[3]);
    *(short4v*)dst = p;
}

// ---------------------------------------------------------------------------
// Bulk fp32 -> bf16 conversion of all inputs.
//  y == 14      : mask scan -> compacted idx list + per-batch count.
//  y in {2..5}  : K/V planes converted DIRECTLY into compacted row order
//                 (gather fused; each block recomputes the tiny mask scan).
//  else         : plain elementwise convert.
// Keys with mask==0 get exactly zero softmax weight in the reference, so we
// drop them from all downstream work.
// ---------------------------------------------------------------------------
struct ConvArgs { const float* src[15]; short* dst[15]; int n4[15]; };

__global__ __launch_bounds__(256) void convert_bf16(ConvArgs ca)
{
    const int a = blockIdx.y;
    if (a == 14) {                      // mask scan (layout detect validated R4)
        if (blockIdx.x != 0) return;
        __shared__ int isByteLayout;
        const int t = threadIdx.x;      // 256 threads; wave w handles batch b=w
        if (t == 0) isByteLayout = 0;
        __syncthreads();
        const int* mi = (const int*)ca.src[14];
        #pragma unroll
        for (int j = 0; j < 4; j++) {
            int v = mi[t*4 + j];        // first 4096 bytes under both layouts
            if (v & ~1) isByteLayout = 1;
        }
        __syncthreads();
        const unsigned char* mb = (const unsigned char*)ca.src[14];
        unsigned char mv[16];
        int lc = 0;
        if (isByteLayout) {
            #pragma unroll
            for (int j = 0; j < 16; j++) { mv[j] = mb[t*16 + j] ? 1 : 0; lc += mv[j]; }
        } else {
            #pragma unroll
            for (int j = 0; j < 16; j++) { mv[j] = mi[t*16 + j] ? 1 : 0; lc += mv[j]; }
        }
        // inclusive scan across the wave (64 lanes cover one batch's 1024 keys)
        const int lane = t & 63, b = t >> 6;
        int sum = lc;
        #pragma unroll
        for (int d = 1; d < 64; d <<= 1) {
            int o = __shfl_up(sum, d, 64);
            if (lane >= d) sum += o;
        }
        int p = sum - lc;               // exclusive base for this lane
        unsigned short* idxOut = (unsigned short*)ca.dst[14];
        int* cntOut = (int*)(idxOut + 4096);
        unsigned short* ib = idxOut + b*1024;
        #pragma unroll
        for (int j = 0; j < 16; j++)
            if (mv[j]) ib[p++] = (unsigned short)(lane*16 + j);
        if (lane == 63) cntOut[b] = sum;
        return;
    }
    if (a >= 2 && a <= 5) {             // gathered convert of K/V planes
        const int t = threadIdx.x;
        const int r0 = blockIdx.x * 16; // 16 out-rows per block, 256 blocks
        const int b  = r0 >> 10;        // never crosses a batch boundary
        __shared__ int isByteLayout;
        __shared__ unsigned short ib[1024];
        __shared__ int scnt;
        if (t == 0) isByteLayout = 0;
        __syncthreads();
        const int* mi = (const int*)ca.src[14];
        #pragma unroll
        for (int j = 0; j < 4; j++) {
            int v = mi[t*4 + j];
            if (v & ~1) isByteLayout = 1;
        }
        __syncthreads();
        if (t < 64) {                   // wave 0: scan for this block's batch
            const unsigned char* mb8 = (const unsigned char*)ca.src[14];
            unsigned char mv[16]; int lc = 0;
            if (isByteLayout) {
                #pragma unroll
                for (int j = 0; j < 16; j++) { mv[j] = mb8[b*1024 + t*16 + j] ? 1 : 0; lc += mv[j]; }
            } else {
                #pragma unroll
                for (int j = 0; j < 16; j++) { mv[j] = mi[b*1024 + t*16 + j] ? 1 : 0; lc += mv[j]; }
            }
            int sum = lc;
            #pragma unroll
            for (int d = 1; d < 64; d <<= 1) {
                int o = __shfl_up(sum, d, 64);
                if (t >= d) sum += o;
            }
            int p = sum - lc;
            #pragma unroll
            for (int j = 0; j < 16; j++)
                if (mv[j]) ib[p++] = (unsigned short)(t*16 + j);
            if (t == 63) scnt = sum;
        }
        __syncthreads();
        const int cb = scnt, L = (cb + 63) & ~63;
        const float* __restrict__ s = ca.src[a];
        short* __restrict__ d = ca.dst[a];
        const int jj = t >> 4, c = t & 15;   // 16 thr per row
        const int j  = r0 + jj;              // global out row
        const int jl = j & 1023;             // row within batch
        if (jl < L) {
            short* dp = d + (size_t)j*RD + c*4;
            if (jl < cb) {
                const float* sp = s + ((size_t)(b*NSEQ) + ib[jl])*RD + c*4;
                #pragma unroll
                for (int u = 0; u < 4; u++) {
                    float4v v = *(const float4v*)(sp + u*64);
                    st4(dp + u*64, v);
                }
            } else {                         // zero pad rows [cnt, ceil64(cnt))
                short4v z = {0,0,0,0};
                #pragma unroll
                for (int u = 0; u < 4; u++) *(short4v*)(dp + u*64) = z;
            }
        }
        return;
    }
    const float* __restrict__ s = ca.src[a];
    short* __restrict__ d = ca.dst[a];
    const int n4 = ca.n4[a];
    for (int i = blockIdx.x*256 + threadIdx.x; i < n4; i += gridDim.x*256) {
        float4v v = *(const float4v*)(s + (size_t)i*4);
        st4(d + (size_t)i*4, v);
    }
}

// ---------------------------------------------------------------------------
// Merged complex projections, all-bf16 (role z = 0:Q, 1:K, 2:V).
// 128(M) x 64(N) tile, 1D grid 768, XCD-chunked role decode with
// z-INTERLEAVED ordering (z = flat%3). DOUBLE-BUFFERED K-loop, K-chunk 32,
// one barrier per chunk, GLOAD16 prefetch in flight during MFMA.
// Source-side XOR swizzle: LDS[row][cg] = G[row][cg^(row&3)], read at
// cg = quad^(l16&3). K/V key-compacted: dead chunks exit early.
// Epilogue: single-pass both-plane LDS transpose -> coalesced 16B stores.
// z<2: Y[bh][n][d]; z==2: Y[bh][d][n].
// ---------------------------------------------------------------------------
struct ProjArgs {
    const short* Xr[3]; const short* Xi[3];
    const short* Wr[3]; const short* Wi[3];
    short* Yr[3]; short* Yi[3];
    const int* cnt;
};

__global__ __launch_bounds__(256) void cgemm_proj(ProjArgs pa)
{
    __shared__ __align__(16) char smemP[49152];   // 48KB unified
    short (*sX)[2][128][32] = (short(*)[2][128][32])smemP;            // 32KB
    short (*sW)[2][64][32]  = (short(*)[2][64][32])(smemP + 32768);   // 16KB

    // XCD-chunked bijective role decode, z fastest (768 = 8 XCDs * 96; 96 = 32*3)
    const int wgid = blockIdx.x;
    const int flat = (wgid & 7) * 96 + (wgid >> 3);
    const int z    = flat % 3;
    const int rem  = flat / 3;                 // 0..255
    const int nx = rem & 7, my = rem >> 3;     // my 0..31
    const int n0 = nx * 64, m0 = my * 128;

    if (z >= 1) {                      // compacted K/V rows: skip dead chunks
        int b  = m0 >> 10;
        int nb = m0 & 1023;
        int L  = (pa.cnt[b] + 63) & ~63;
        if (nb >= L) return;
    }
    const short* __restrict__ X_r = pa.Xr[z];
    const short* __restrict__ X_i = pa.Xi[z];
    const short* __restrict__ W_r = pa.Wr[z];
    const short* __restrict__ W_i = pa.Wi[z];
    short* __restrict__ Y_r = pa.Yr[z];
    short* __restrict__ Y_i = pa.Yi[z];
    const int transposeOut = (z == 2);

    const int tid  = threadIdx.x;
    const int lane = tid & 63, wave = tid >> 6;
    const int quad = lane >> 4, l16 = lane & 15;
    const int lrow = lane >> 2;              // 0..15 (staging row-within-16)
    const int scg  = (lane & 3) ^ (lrow & 3);// pre-swizzled source col-group

    const short nk = (short)0x8000;
    const short8 neg = {nk,nk,nk,nk,nk,nk,nk,nk};

    float4v zf = {0.f,0.f,0.f,0.f};
    float4v Yr[2][4], Yi[2][4];
    #pragma unroll
    for (int ms = 0; ms < 2; ms++)
        #pragma unroll
        for (int t = 0; t < 4; t++) { Yr[ms][t] = zf; Yi[ms][t] = zf; }

    // ---- staging: chunk kc (shorts) into buffer bf ----
    #define PROJ_STAGE(kc, bf)                                                \
        if (wave < 2) {                                                       \
            const short* gp = wave ? X_i : X_r;                               \
            short* lp = &sX[bf][wave][0][0];                                  \
            _Pragma("unroll")                                                 \
            for (int j = 0; j < 8; j++)                                       \
                GLOAD16(gp + (size_t)(m0 + j*16 + lrow)*RD + (kc) + scg*8,    \
                        lp + j*512);                                          \
        } else {                                                              \
            const short* gp = (wave == 3) ? W_i : W_r;                        \
            short* lp = &sW[bf][wave - 2][0][0];                              \
            _Pragma("unroll")                                                 \
            for (int j = 0; j < 4; j++)                                       \
                GLOAD16(gp + (size_t)(n0 + j*16 + lrow)*RD + (kc) + scg*8,    \
                        lp + j*512);                                          \
        }

    PROJ_STAGE(0, 0);                      // prologue: chunk 0 -> buf 0

    const int xsh = l16 & 3;
    for (int c = 0; c < 8; c++) {          // 8 chunks of K=32
        __syncthreads();                   // chunk c staged; buf c&1 free'd
        if (c + 1 < 8) { PROJ_STAGE((c + 1)*32, (c + 1) & 1); }
        const int bf = c & 1;
        const int u = (quad ^ xsh) * 8;

        short8 fxr[2], fxi[2], fxin[2];
        #pragma unroll
        for (int ms = 0; ms < 2; ms++) {
            int row = wave*32 + ms*16 + l16;
            fxr[ms]  = *(short8*)&sX[bf][0][row][u];
            fxi[ms]  = *(short8*)&sX[bf][1][row][u];
            fxin[ms] = fxi[ms] ^ neg;
        }
        #pragma unroll
        for (int t = 0; t < 4; t++) {
            short8 wr = *(short8*)&sW[bf][0][t*16 + l16][u];
            short8 wi = *(short8*)&sW[bf][1][t*16 + l16][u];
            #pragma unroll
            for (int ms = 0; ms < 2; ms++) {
                Yr[ms][t] = MFMA16(fxr[ms],  wr, Yr[ms][t]);
                Yr[ms][t] = MFMA16(fxin[ms], wi, Yr[ms][t]);   // -Xi*Wi
                Yi[ms][t] = MFMA16(fxr[ms],  wi, Yi[ms][t]);
                Yi[ms][t] = MFMA16(fxi[ms],  wr, Yi[ms][t]);
            }
        }
    }
    #undef PROJ_STAGE

    // ---- epilogue: single-pass both-plane LDS transpose -> 16B stores ----
    const int b = m0 >> 10, h = n0 >> 6, nb = m0 & 1023;
    short* sT = (short*)smemP;
    const int PLSZ = transposeOut ? 8448 : 8704;   // shorts per plane
    __syncthreads();                               // all staging reads done
    #pragma unroll
    for (int ms = 0; ms < 2; ms++)
        #pragma unroll
        for (int t = 0; t < 4; t++)
            #pragma unroll
            for (int r = 0; r < 4; r++) {
                int rr = wave*32 + ms*16 + quad*4 + r;  // n-local (0..127)
                int cc = t*16 + l16;                    // d (0..63)
                if (!transposeOut) {
                    sT[rr*68 + cc]          = f2b(Yr[ms][t][r]);
                    sT[PLSZ + rr*68 + cc]   = f2b(Yi[ms][t][r]);
                } else {
                    sT[cc*132 + rr]         = f2b(Yr[ms][t][r]);
                    sT[PLSZ + cc*132 + rr]  = f2b(Yi[ms][t][r]);
                }
            }
    __syncthreads();
    short* Yp[2] = { Y_r, Y_i };
    #pragma unroll
    for (int p = 0; p < 2; p++) {
        #pragma unroll
        for (int it = 0; it < 4; it++) {
            int idx = it*256 + tid;           // 0..1023 16B-units
            int rr, c8;
            size_t o;
            const short* sp;
            if (!transposeOut) {              // 128 rows x 64 cols
                rr = idx >> 3; c8 = (idx & 7)*8;
                sp = &sT[p*PLSZ + rr*68 + c8];
                o = (((size_t)(b*NHEAD + h))*NSEQ + nb + rr)*HD + c8;
            } else {                          // 64 rows(d) x 128 cols(n)
                rr = idx >> 4; c8 = (idx & 15)*8;
                sp = &sT[p*PLSZ + rr*132 + c8];
                o = (((size_t)(b*NHEAD + h))*HD + rr)*NSEQ + nb + c8;
            }
            short4v a = *(short4v*)sp;
            short4v bq = *(short4v*)(sp + 4);
            short8 v8 = { a[0],a[1],a[2],a[3], bq[0],bq[1],bq[2],bq[3] };
            *(short8*)&Yp[p][o] = v8;
        }
    }
}

// ---------------------------------------------------------------------------
// Flash attention over KEY-COMPACTED K/V + FUSED OUTPUT PROJECTION.
// Main loop: DOUBLE-BUFFERED single-barrier K-loop (unchanged from the
// 147.3us best). Epilogue: instead of writing A planes to global (16MB
// round trip + a 4th kernel), each block's normalized 64(q)x64(d) A-tile
// goes to LDS in XOR-swizzled fragment layout, then all 8 waves compute
// the 64x256x64 complex GEMM against WO's h-slice (bf16, L2-resident,
// read direct) and atomicAdd fp32 partials into Out (head-sum via atomics;
// Out pre-zeroed by hipMemsetAsync). 8 waves = 4 q-strips x 2 key-halves;
// grid 512 qt-major (XCD = bh%8). 75KB LDS -> 2 blk/CU.
// ---------------------------------------------------------------------------
__global__ __launch_bounds__(512) void attn_mfma(
    const short* __restrict__ Qp_r, const short* __restrict__ Qp_i,
    const short* __restrict__ Kp_r, const short* __restrict__ Kp_i,
    const short* __restrict__ Vp_r, const short* __restrict__ Vp_i,
    const int* __restrict__ cnt,
    const short* __restrict__ WOr, const short* __restrict__ WOi,
    float* __restrict__ Out, int writeImagPlane)
{
    __shared__ __align__(16) char smem[75776];
    // buf b at smem + b*32768: Kr +0, Ki +8192, Vr +16384, Vi +24576
    short (*sP)[16][40] = (short(*)[16][40])(smem + 65536);  // 8 waves, 10KB

    const int tid  = threadIdx.x;
    const int lane = tid & 63, wave = tid >> 6;      // 0..7
    const int quad = lane >> 4, l16 = lane & 15;
    const int sw8  = l16 & 7;
    const int qstrip = wave >> 1;                    // 0..3
    const int khalf  = wave & 1;                     // 0..1
    const int qt = blockIdx.x >> 5;                  // qt-major
    const int bh = blockIdx.x & 31;                  // XCD = bh % 8
    const int b  = bh >> 3, h = bh & 7;
    const size_t base = (size_t)bh * (NSEQ*HD);

    const int rsub = lane >> 3;
    const int colg = (lane & 7) ^ rsub;

    const int cb = cnt[b];
    const int nt = (cb + 63) >> 6;                   // compacted key tiles

    // this wave's staging plane (0:Kr 1:Ki 2:Vr 3:Vi), 4 chunks of 1KB
    const int splane = wave >> 1;
    const short* sgp = (splane == 0) ? Kp_r : (splane == 1) ? Kp_i
                     : (splane == 2) ? Vp_r : Vp_i;
    const int sisV = (splane >= 2);
    const int soff = splane * 8192;

    // ---- Q fragments direct from global (once, out of loop) ----
    const short nk = (short)0x8000;
    const short8 neg = {nk,nk,nk,nk,nk,nk,nk,nk};
    short8 fqr[2], fqi[2], fqrn[2];
    #pragma unroll
    for (int ds = 0; ds < 2; ds++) {
        size_t qo = base + (size_t)(qt*64 + qstrip*16 + l16)*HD + ds*32 + quad*8;
        fqr[ds]  = *(const short8*)&Qp_r[qo];
        fqi[ds]  = *(const short8*)&Qp_i[qo];
        fqrn[ds] = fqr[ds] ^ neg;
    }

    float4v zf = {0.f,0.f,0.f,0.f};
    float4v Or[4], Oi[4];
    float lrow[4];
    #pragma unroll
    for (int t = 0; t < 4; t++) { Or[t] = zf; Oi[t] = zf; }
    #pragma unroll
    for (int r = 0; r < 4; r++) lrow[r] = 0.f;

    const float C2 = 0.18033688f;   // 0.125 * log2(e)

    // ---- prologue: stage tile 0 into buf 0 ----
    if (nt > 0) {
        short* lp = (short*)(smem + soff);
        #pragma unroll
        for (int jj = 0; jj < 4; jj++) {
            int j = (wave & 1)*4 + jj;
            int row = j*8 + rsub;
            const short* g = sisV
                ? sgp + base + (size_t)row*NSEQ + colg*8
                : sgp + base + (size_t)row*HD + colg*8;
            GLOAD16(g, lp + j*512);
        }
    }

    for (int kt = 0; kt < nt; kt++) {
        __syncthreads();    // buf[kt&1] staged (vmcnt drained); prev reads done

        // ---- issue async staging of tile kt+1 into the other buffer ----
        if (kt + 1 < nt) {
            const int kn = (kt + 1) * 64;
            short* lp = (short*)(smem + ((kt + 1) & 1)*32768 + soff);
            #pragma unroll
            for (int jj = 0; jj < 4; jj++) {
                int j = (wave & 1)*4 + jj;
                int row = j*8 + rsub;
                const short* g = sisV
                    ? sgp + base + (size_t)row*NSEQ + kn + colg*8
                    : sgp + base + (size_t)(kn + row)*HD + colg*8;
                GLOAD16(g, lp + j*512);
            }
        }

        // ---- compute from buf[kt&1] ----
        const char* buf = smem + (kt & 1)*32768;
        short (*sK0)[64] = (short(*)[64])(buf);
        short (*sK1)[64] = (short(*)[64])(buf + 8192);
        short (*sV0)[64] = (short(*)[64])(buf + 16384);
        short (*sV1)[64] = (short(*)[64])(buf + 24576);
        const int k0 = kt*64;

        // S = Q conj(K)^T over this wave's 32-key half
        float4v Sr[2], Si[2];
        Sr[0] = zf; Sr[1] = zf; Si[0] = zf; Si[1] = zf;
        __builtin_amdgcn_s_setprio(1);
        #pragma unroll
        for (int t = 0; t < 2; t++)
            #pragma unroll
            for (int ds = 0; ds < 2; ds++) {
                int u = ((ds*4 + quad) ^ sw8) * 8;
                int krow = khalf*32 + t*16 + l16;
                short8 kr = *(short8*)&sK0[krow][u];
                short8 ki = *(short8*)&sK1[krow][u];
                Sr[t] = MFMA16(fqr[ds],  kr, Sr[t]);
                Sr[t] = MFMA16(fqi[ds],  ki, Sr[t]);
                Si[t] = MFMA16(fqi[ds],  kr, Si[t]);
                Si[t] = MFMA16(fqrn[ds], ki, Si[t]);
            }
        __builtin_amdgcn_s_setprio(0);

        // e = exp(|S|/8) (no max shift), per-lane l, P strip.
        // Valid iff compacted key index < cnt[b]; pad V cols are zero.
        #pragma unroll
        for (int t = 0; t < 2; t++) {
            bool mv = (k0 + khalf*32 + t*16 + l16) < cb;
            #pragma unroll
            for (int r = 0; r < 4; r++) {
                float a = Sr[t][r], c = Si[t][r];
                float x = fmaf(a, a, c*c);
                float s = __builtin_amdgcn_sqrtf(x);
                float e = mv ? __builtin_amdgcn_exp2f(C2 * s) : 0.f;
                lrow[r] += e;
                sP[wave][quad*4 + r][t*16 + l16] = f2b(e);
            }
        }

        // O += P @ V over this wave's 32 keys (K=32, one frag)
        {
            short8 fp = *(short8*)&sP[wave][l16][quad*8];
            __builtin_amdgcn_s_setprio(1);
            #pragma unroll
            for (int t = 0; t < 4; t++) {
                int u = ((khalf*4 + quad) ^ sw8) * 8;
                short8 vr = *(short8*)&sV0[t*16 + l16][u];
                short8 vi = *(short8*)&sV1[t*16 + l16][u];
                Or[t] = MFMA16(fp, vr, Or[t]);
                Oi[t] = MFMA16(fp, vi, Oi[t]);
            }
            __builtin_amdgcn_s_setprio(0);
        }
    }

    // ---- combine key-half partners (khalf 1 -> 0) through reused LDS ----
    __syncthreads();                          // all buf/sP reads done
    float* sC = (float*)smem;                 // 32KB O partials
    float* sL = (float*)(smem + 32768);       // 4KB  l partials
    short* sA2r = (short*)(smem + 36864);     // 8KB  normalized A real (swz)
    short* sA2i = (short*)(smem + 45056);     // 8KB  normalized A imag (swz)
    if (khalf == 1) {
        #pragma unroll
        for (int t = 0; t < 4; t++)
            #pragma unroll
            for (int r = 0; r < 4; r++) {
                int o8 = ((qstrip*4 + t)*64 + lane)*8 + r*2;
                sC[o8]     = Or[t][r];
                sC[o8 + 1] = Oi[t][r];
            }
        int lo = (qstrip*64 + lane)*4;
        #pragma unroll
        for (int r = 0; r < 4; r++) sL[lo + r] = lrow[r];
    }
    __syncthreads();
    if (khalf == 0) {
        #pragma unroll
        for (int t = 0; t < 4; t++)
            #pragma unroll
            for (int r = 0; r < 4; r++) {
                int o8 = ((qstrip*4 + t)*64 + lane)*8 + r*2;
                Or[t][r] += sC[o8];
                Oi[t][r] += sC[o8 + 1];
            }
        int lo = (qstrip*64 + lane)*4;
        float inv[4];
        #pragma unroll
        for (int r = 0; r < 4; r++) {
            float ls = lrow[r] + sL[lo + r];
            ls += __shfl_xor(ls, 1, 64);
            ls += __shfl_xor(ls, 2, 64);
            ls += __shfl_xor(ls, 4, 64);
            ls += __shfl_xor(ls, 8, 64);
            inv[r] = (ls > 0.f) ? 1.f/ls : 0.f;
        }
        // normalized A tile -> LDS, XOR-swizzled fragment layout:
        // addr = q*64 + (cg ^ (q&7))*8 + (d&7), cg = d>>3
        #pragma unroll
        for (int t = 0; t < 4; t++)
            #pragma unroll
            for (int r = 0; r < 4; r++) {
                int q = qstrip*16 + quad*4 + r;        // local q (0..63)
                int d = t*16 + l16;                    // local d (0..63)
                int ao = q*64 + ((d >> 3) ^ (q & 7))*8 + (d & 7);
                sA2r[ao] = f2b(Or[t][r] * inv[r]);
                sA2i[ao] = f2b(Oi[t][r] * inv[r]);
            }
    }
    __syncthreads();                          // A tile visible to all waves

    // ---- fused output projection: A(64x64) @ WO_h^T -> atomicAdd Out ----
    // Wave owns out-cols [wave*32, wave*32+32). K = this head's 64 dims.
    {
        const size_t TOT = (size_t)NBATCH * NSEQ * RD;   // 1,048,576
        float4v aR[4][2], aI[4][2];
        #pragma unroll
        for (int m = 0; m < 4; m++)
            #pragma unroll
            for (int nf = 0; nf < 2; nf++) { aR[m][nf] = zf; aI[m][nf] = zf; }
        #pragma unroll
        for (int ks = 0; ks < 2; ks++) {
            short8 wr[2], wi[2];
            #pragma unroll
            for (int nf = 0; nf < 2; nf++) {
                int n = wave*32 + nf*16 + l16;         // WO row (out col)
                size_t wo = (size_t)n*NHD + h*HD + ks*32 + quad*8;
                wr[nf] = *(const short8*)&WOr[wo];
                wi[nf] = *(const short8*)&WOi[wo];
            }
            #pragma unroll
            for (int m = 0; m < 4; m++) {
                int u = ((ks*4 + quad) ^ sw8) * 8;     // q&7 == l16&7 cancels
                short8 ar  = *(short8*)&sA2r[(m*16 + l16)*64 + u];
                short8 ai  = *(short8*)&sA2i[(m*16 + l16)*64 + u];
                short8 ain = ai ^ neg;
                #pragma unroll
                for (int nf = 0; nf < 2; nf++) {
                    aR[m][nf] = MFMA16(ar,  wr[nf], aR[m][nf]);
                    aR[m][nf] = MFMA16(ain, wi[nf], aR[m][nf]);   // -Ai*Wi
                    aI[m][nf] = MFMA16(ar,  wi[nf], aI[m][nf]);
                    aI[m][nf] = MFMA16(ai,  wr[nf], aI[m][nf]);
                }
            }
        }
        #pragma unroll
        for (int m = 0; m < 4; m++)
            #pragma unroll
            for (int nf = 0; nf < 2; nf++)
                #pragma unroll
                for (int r = 0; r < 4; r++) {
                    int row = qt*64 + m*16 + quad*4 + r;
                    int col = wave*32 + nf*16 + l16;
                    size_t o = ((size_t)(b*NSEQ + row))*RD + col;
                    atomicAdd(&Out[o], aR[m][nf][r]);
                    if (writeImagPlane) atomicAdd(&Out[o + TOT], aI[m][nf][r]);
                }
    }
}

// ---------------------------------------------------------------------------
extern "C" void kernel_launch(void* const* d_in, const int* in_sizes, int n_in,
                              void* d_out, int out_size, void* d_ws, size_t ws_size,
                              hipStream_t stream)
{
    float* out = (float*)d_out;

    const size_t P = (size_t)NBATCH * NHEAD * NSEQ * HD;   // 2,097,152
    const size_t H = (size_t)NBATCH * NSEQ * RD;           // 1,048,576
    const size_t WSZ = (size_t)NHD * RD;                   // 131,072

    short* bws = (short*)d_ws;
    // bf16 projected planes [0, 24MB)
    short* Qpr = bws + 0*P;  short* Qpi = bws + 1*P;
    short* Kpr = bws + 2*P;  short* Kpi = bws + 3*P;
    short* Vpr = bws + 4*P;  short* Vpi = bws + 5*P;
    // converted-input region @ 24MB (dead after cgemm_proj, except WO)
    short* conv = bws + 6*P;
    short* cX[6]; for (int i = 0; i < 6; i++) cX[i] = conv + i*H;       // 12MB
    short* cW[6]; for (int i = 0; i < 6; i++) cW[i] = conv + 6*H + i*WSZ;
    short* cWOr = conv + 6*H + 6*WSZ;
    short* cWOi = conv + 6*H + 7*WSZ;
    // mask compaction: idx[4][1024] (ushort) + cnt[4] (int)
    unsigned short* midx = (unsigned short*)(conv + 6*H + 8*WSZ);
    int* mcnt = (int*)(midx + 4096);

    const size_t TOT = (size_t)NBATCH * NSEQ * RD;
    const int writeImagPlane = ((size_t)out_size >= 2*TOT) ? 1 : 0;

    ConvArgs ca;
    for (int i = 0; i < 6; i++) {
        ca.src[i] = (const float*)d_in[i];  ca.dst[i] = cX[i];  ca.n4[i] = (int)(H/4);
    }
    for (int i = 0; i < 6; i++) {
        ca.src[6+i] = (const float*)d_in[6+i]; ca.dst[6+i] = cW[i]; ca.n4[6+i] = (int)(WSZ/4);
    }
    ca.src[12] = (const float*)d_in[12]; ca.dst[12] = cWOr; ca.n4[12] = (int)(WSZ/4);
    ca.src[13] = (const float*)d_in[13]; ca.dst[13] = cWOi; ca.n4[13] = (int)(WSZ/4);
    ca.src[14] = (const float*)d_in[14]; ca.dst[14] = (short*)midx; ca.n4[14] = 0;

    ProjArgs pa;
    pa.Xr[0] = cX[0]; pa.Xi[0] = cX[1];
    pa.Xr[1] = cX[2]; pa.Xi[1] = cX[3];   // gathered in convert
    pa.Xr[2] = cX[4]; pa.Xi[2] = cX[5];   // gathered in convert
    pa.Wr[0] = cW[0]; pa.Wi[0] = cW[1];
    pa.Wr[1] = cW[2]; pa.Wi[1] = cW[3];
    pa.Wr[2] = cW[4]; pa.Wi[2] = cW[5];
    pa.Yr[0] = Qpr; pa.Yi[0] = Qpi;
    pa.Yr[1] = Kpr; pa.Yi[1] = Kpi;
    pa.Yr[2] = Vpr; pa.Yi[2] = Vpi;
    pa.cnt = mcnt;

    // zero the output accumulation target (capturable stream op)
    hipMemsetAsync(out, 0, (size_t)(1 + writeImagPlane) * TOT * sizeof(float),
                   stream);

    convert_bf16<<<dim3(256, 15), 256, 0, stream>>>(ca);
    cgemm_proj<<<dim3(768), 256, 0, stream>>>(pa);
    attn_mfma<<<dim3(512), 512, 0, stream>>>(Qpr, Qpi, Kpr, Kpi, Vpr, Vpi,
                                             mcnt, cWOr, cWOi, out,
                                             writeImagPlane);
}

// Round 13
// 146.849 us; speedup vs baseline: 1.1661x; 1.1661x over previous
//
#include <hip/hip_runtime.h>
#include <hip/hip_bf16.h>

#define NBATCH 4
#define NSEQ   1024
#define RD     256
#define NHEAD  8
#define HD     64
#define NHD    512   // NHEAD*HD

typedef __attribute__((ext_vector_type(8))) short  short8;
typedef __attribute__((ext_vector_type(4))) short  short4v;
typedef __attribute__((ext_vector_type(4))) float  float4v;

#define MFMA16(a,b,c) __builtin_amdgcn_mfma_f32_16x16x32_bf16(a,b,c,0,0,0)

typedef const void __attribute__((address_space(1)))* gas_t;
typedef void __attribute__((address_space(3)))* las_t;
#define GLOAD16(g, l) __builtin_amdgcn_global_load_lds((gas_t)(g), (las_t)(l), 16, 0, 0)

// Native bf16 cast (RNE, same bits as manual round) — compiler emits fast cvt.
static __device__ __forceinline__ short f2b(float f) {
    __hip_bfloat16 h = __float2bfloat16(f);
    union { __hip_bfloat16 h; short s; } u; u.h = h;
    return u.s;
}
static __device__ __forceinline__ void st4(short* dst, float4v v) {
    short4v p;
    p[0] = f2b(v[0]); p[1] = f2b(v[1]);
    p[2] = f2b(v[2]); p[3] = f2b(v[3]);
    *(short4v*)dst = p;
}

// ---------------------------------------------------------------------------
// Bulk fp32 -> bf16 conversion of all inputs.
//  y == 14      : mask scan -> compacted idx list + per-batch count.
//  y in {2..5}  : K/V planes converted DIRECTLY into compacted row order
//                 (gather fused; each block recomputes the tiny mask scan).
//  else         : plain elementwise convert.
// Keys with mask==0 get exactly zero softmax weight in the reference, so we
// drop them from all downstream work.
// ---------------------------------------------------------------------------
struct ConvArgs { const float* src[15]; short* dst[15]; int n4[15]; };

__global__ __launch_bounds__(256) void convert_bf16(ConvArgs ca)
{
    const int a = blockIdx.y;
    if (a == 14) {                      // mask scan (layout detect validated R4)
        if (blockIdx.x != 0) return;
        __shared__ int isByteLayout;
        const int t = threadIdx.x;      // 256 threads; wave w handles batch b=w
        if (t == 0) isByteLayout = 0;
        __syncthreads();
        const int* mi = (const int*)ca.src[14];
        #pragma unroll
        for (int j = 0; j < 4; j++) {
            int v = mi[t*4 + j];        // first 4096 bytes under both layouts
            if (v & ~1) isByteLayout = 1;
        }
        __syncthreads();
        const unsigned char* mb = (const unsigned char*)ca.src[14];
        unsigned char mv[16];
        int lc = 0;
        if (isByteLayout) {
            #pragma unroll
            for (int j = 0; j < 16; j++) { mv[j] = mb[t*16 + j] ? 1 : 0; lc += mv[j]; }
        } else {
            #pragma unroll
            for (int j = 0; j < 16; j++) { mv[j] = mi[t*16 + j] ? 1 : 0; lc += mv[j]; }
        }
        // inclusive scan across the wave (64 lanes cover one batch's 1024 keys)
        const int lane = t & 63, b = t >> 6;
        int sum = lc;
        #pragma unroll
        for (int d = 1; d < 64; d <<= 1) {
            int o = __shfl_up(sum, d, 64);
            if (lane >= d) sum += o;
        }
        int p = sum - lc;               // exclusive base for this lane
        unsigned short* idxOut = (unsigned short*)ca.dst[14];
        int* cntOut = (int*)(idxOut + 4096);
        unsigned short* ib = idxOut + b*1024;
        #pragma unroll
        for (int j = 0; j < 16; j++)
            if (mv[j]) ib[p++] = (unsigned short)(lane*16 + j);
        if (lane == 63) cntOut[b] = sum;
        return;
    }
    if (a >= 2 && a <= 5) {             // gathered convert of K/V planes
        const int t = threadIdx.x;
        const int r0 = blockIdx.x * 16; // 16 out-rows per block, 256 blocks
        const int b  = r0 >> 10;        // never crosses a batch boundary
        __shared__ int isByteLayout;
        __shared__ unsigned short ib[1024];
        __shared__ int scnt;
        if (t == 0) isByteLayout = 0;
        __syncthreads();
        const int* mi = (const int*)ca.src[14];
        #pragma unroll
        for (int j = 0; j < 4; j++) {
            int v = mi[t*4 + j];
            if (v & ~1) isByteLayout = 1;
        }
        __syncthreads();
        if (t < 64) {                   // wave 0: scan for this block's batch
            const unsigned char* mb8 = (const unsigned char*)ca.src[14];
            unsigned char mv[16]; int lc = 0;
            if (isByteLayout) {
                #pragma unroll
                for (int j = 0; j < 16; j++) { mv[j] = mb8[b*1024 + t*16 + j] ? 1 : 0; lc += mv[j]; }
            } else {
                #pragma unroll
                for (int j = 0; j < 16; j++) { mv[j] = mi[b*1024 + t*16 + j] ? 1 : 0; lc += mv[j]; }
            }
            int sum = lc;
            #pragma unroll
            for (int d = 1; d < 64; d <<= 1) {
                int o = __shfl_up(sum, d, 64);
                if (t >= d) sum += o;
            }
            int p = sum - lc;
            #pragma unroll
            for (int j = 0; j < 16; j++)
                if (mv[j]) ib[p++] = (unsigned short)(t*16 + j);
            if (t == 63) scnt = sum;
        }
        __syncthreads();
        const int cb = scnt, L = (cb + 63) & ~63;
        const float* __restrict__ s = ca.src[a];
        short* __restrict__ d = ca.dst[a];
        const int jj = t >> 4, c = t & 15;   // 16 thr per row
        const int j  = r0 + jj;              // global out row
        const int jl = j & 1023;             // row within batch
        if (jl < L) {
            short* dp = d + (size_t)j*RD + c*4;
            if (jl < cb) {
                const float* sp = s + ((size_t)(b*NSEQ) + ib[jl])*RD + c*4;
                #pragma unroll
                for (int u = 0; u < 4; u++) {
                    float4v v = *(const float4v*)(sp + u*64);
                    st4(dp + u*64, v);
                }
            } else {                         // zero pad rows [cnt, ceil64(cnt))
                short4v z = {0,0,0,0};
                #pragma unroll
                for (int u = 0; u < 4; u++) *(short4v*)(dp + u*64) = z;
            }
        }
        return;
    }
    const float* __restrict__ s = ca.src[a];
    short* __restrict__ d = ca.dst[a];
    const int n4 = ca.n4[a];
    for (int i = blockIdx.x*256 + threadIdx.x; i < n4; i += gridDim.x*256) {
        float4v v = *(const float4v*)(s + (size_t)i*4);
        st4(d + (size_t)i*4, v);
    }
}

// ---------------------------------------------------------------------------
// Merged complex projections, all-bf16 (role z = 0:Q, 1:K, 2:V).
// 128(M) x 64(N) tile, 1D grid 768, XCD-chunked role decode with
// z-INTERLEAVED ordering (z = flat%3): even Q/K/V mix per XCD (dead K/V
// panels from key compaction spread evenly). DOUBLE-BUFFERED K-loop,
// K-chunk 32, one barrier per chunk, GLOAD16 prefetch in flight during
// MFMA. Source-side XOR swizzle: LDS[row][cg] = G[row][cg^(row&3)], read
// at cg = quad^(l16&3). Epilogue: single-pass both-plane LDS transpose.
// z<2: Y[bh][n][d]; z==2: Y[bh][d][n].
// ---------------------------------------------------------------------------
struct ProjArgs {
    const short* Xr[3]; const short* Xi[3];
    const short* Wr[3]; const short* Wi[3];
    short* Yr[3]; short* Yi[3];
    const int* cnt;
};

__global__ __launch_bounds__(256) void cgemm_proj(ProjArgs pa)
{
    __shared__ __align__(16) char smemP[49152];   // 48KB unified
    short (*sX)[2][128][32] = (short(*)[2][128][32])smemP;            // 32KB
    short (*sW)[2][64][32]  = (short(*)[2][64][32])(smemP + 32768);   // 16KB

    // XCD-chunked bijective role decode, z fastest (768 = 8 XCDs * 96; 96 = 32*3)
    const int wgid = blockIdx.x;
    const int flat = (wgid & 7) * 96 + (wgid >> 3);
    const int z    = flat % 3;
    const int rem  = flat / 3;                 // 0..255
    const int nx = rem & 7, my = rem >> 3;     // my 0..31
    const int n0 = nx * 64, m0 = my * 128;

    if (z >= 1) {                      // compacted K/V rows: skip dead chunks
        int b  = m0 >> 10;
        int nb = m0 & 1023;
        int L  = (pa.cnt[b] + 63) & ~63;
        if (nb >= L) return;
    }
    const short* __restrict__ X_r = pa.Xr[z];
    const short* __restrict__ X_i = pa.Xi[z];
    const short* __restrict__ W_r = pa.Wr[z];
    const short* __restrict__ W_i = pa.Wi[z];
    short* __restrict__ Y_r = pa.Yr[z];
    short* __restrict__ Y_i = pa.Yi[z];
    const int transposeOut = (z == 2);

    const int tid  = threadIdx.x;
    const int lane = tid & 63, wave = tid >> 6;
    const int quad = lane >> 4, l16 = lane & 15;
    const int lrow = lane >> 2;              // 0..15 (staging row-within-16)
    const int scg  = (lane & 3) ^ (lrow & 3);// pre-swizzled source col-group

    const short nk = (short)0x8000;
    const short8 neg = {nk,nk,nk,nk,nk,nk,nk,nk};

    float4v zf = {0.f,0.f,0.f,0.f};
    float4v Yr[2][4], Yi[2][4];
    #pragma unroll
    for (int ms = 0; ms < 2; ms++)
        #pragma unroll
        for (int t = 0; t < 4; t++) { Yr[ms][t] = zf; Yi[ms][t] = zf; }

    // ---- staging: chunk kc (shorts) into buffer bf ----
    #define PROJ_STAGE(kc, bf)                                                \
        if (wave < 2) {                                                       \
            const short* gp = wave ? X_i : X_r;                               \
            short* lp = &sX[bf][wave][0][0];                                  \
            _Pragma("unroll")                                                 \
            for (int j = 0; j < 8; j++)                                       \
                GLOAD16(gp + (size_t)(m0 + j*16 + lrow)*RD + (kc) + scg*8,    \
                        lp + j*512);                                          \
        } else {                                                              \
            const short* gp = (wave == 3) ? W_i : W_r;                        \
            short* lp = &sW[bf][wave - 2][0][0];                              \
            _Pragma("unroll")                                                 \
            for (int j = 0; j < 4; j++)                                       \
                GLOAD16(gp + (size_t)(n0 + j*16 + lrow)*RD + (kc) + scg*8,    \
                        lp + j*512);                                          \
        }

    PROJ_STAGE(0, 0);                      // prologue: chunk 0 -> buf 0

    const int xsh = l16 & 3;
    for (int c = 0; c < 8; c++) {          // 8 chunks of K=32
        __syncthreads();                   // chunk c staged; buf c&1 free'd
        if (c + 1 < 8) { PROJ_STAGE((c + 1)*32, (c + 1) & 1); }
        const int bf = c & 1;
        const int u = (quad ^ xsh) * 8;

        short8 fxr[2], fxi[2], fxin[2];
        #pragma unroll
        for (int ms = 0; ms < 2; ms++) {
            int row = wave*32 + ms*16 + l16;
            fxr[ms]  = *(short8*)&sX[bf][0][row][u];
            fxi[ms]  = *(short8*)&sX[bf][1][row][u];
            fxin[ms] = fxi[ms] ^ neg;
        }
        #pragma unroll
        for (int t = 0; t < 4; t++) {
            short8 wr = *(short8*)&sW[bf][0][t*16 + l16][u];
            short8 wi = *(short8*)&sW[bf][1][t*16 + l16][u];
            #pragma unroll
            for (int ms = 0; ms < 2; ms++) {
                Yr[ms][t] = MFMA16(fxr[ms],  wr, Yr[ms][t]);
                Yr[ms][t] = MFMA16(fxin[ms], wi, Yr[ms][t]);   // -Xi*Wi
                Yi[ms][t] = MFMA16(fxr[ms],  wi, Yi[ms][t]);
                Yi[ms][t] = MFMA16(fxi[ms],  wr, Yi[ms][t]);
            }
        }
    }
    #undef PROJ_STAGE

    // ---- epilogue: single-pass both-plane LDS transpose -> 16B stores ----
    const int b = m0 >> 10, h = n0 >> 6, nb = m0 & 1023;
    short* sT = (short*)smemP;
    const int PLSZ = transposeOut ? 8448 : 8704;   // shorts per plane
    __syncthreads();                               // all staging reads done
    #pragma unroll
    for (int ms = 0; ms < 2; ms++)
        #pragma unroll
        for (int t = 0; t < 4; t++)
            #pragma unroll
            for (int r = 0; r < 4; r++) {
                int rr = wave*32 + ms*16 + quad*4 + r;  // n-local (0..127)
                int cc = t*16 + l16;                    // d (0..63)
                if (!transposeOut) {
                    sT[rr*68 + cc]          = f2b(Yr[ms][t][r]);
                    sT[PLSZ + rr*68 + cc]   = f2b(Yi[ms][t][r]);
                } else {
                    sT[cc*132 + rr]         = f2b(Yr[ms][t][r]);
                    sT[PLSZ + cc*132 + rr]  = f2b(Yi[ms][t][r]);
                }
            }
    __syncthreads();
    short* Yp[2] = { Y_r, Y_i };
    #pragma unroll
    for (int p = 0; p < 2; p++) {
        #pragma unroll
        for (int it = 0; it < 4; it++) {
            int idx = it*256 + tid;           // 0..1023 16B-units
            int rr, c8;
            size_t o;
            const short* sp;
            if (!transposeOut) {              // 128 rows x 64 cols
                rr = idx >> 3; c8 = (idx & 7)*8;
                sp = &sT[p*PLSZ + rr*68 + c8];
                o = (((size_t)(b*NHEAD + h))*NSEQ + nb + rr)*HD + c8;
            } else {                          // 64 rows(d) x 128 cols(n)
                rr = idx >> 4; c8 = (idx & 15)*8;
                sp = &sT[p*PLSZ + rr*132 + c8];
                o = (((size_t)(b*NHEAD + h))*HD + rr)*NSEQ + nb + c8;
            }
            short4v a = *(short4v*)sp;
            short4v bq = *(short4v*)(sp + 4);
            short8 v8 = { a[0],a[1],a[2],a[3], bq[0],bq[1],bq[2],bq[3] };
            *(short8*)&Yp[p][o] = v8;
        }
    }
}

// ---------------------------------------------------------------------------
// Flash attention over KEY-COMPACTED K/V: tile count nt = ceil(cnt[b]/64).
// DOUBLE-BUFFERED single-barrier K-loop; GLOAD16 prefetch of tile kt+1
// during compute of kt. 8 waves = 4 q-strips x 2 key-halves, 64 q rows;
// grid 512 qt-major (XCD = bh%8). s_setprio(1) around MFMA clusters.
// No-max softmax gated by compacted index < cnt; pad V columns are zeros.
// Additive (O,l) partials combined at end via LDS. 75KB LDS -> 2 blk/CU.
// ---------------------------------------------------------------------------
__global__ __launch_bounds__(512) void attn_mfma(
    const short* __restrict__ Qp_r, const short* __restrict__ Qp_i,
    const short* __restrict__ Kp_r, const short* __restrict__ Kp_i,
    const short* __restrict__ Vp_r, const short* __restrict__ Vp_i,
    const int* __restrict__ cnt,
    short* __restrict__ Ar, short* __restrict__ Ai)
{
    __shared__ __align__(16) char smem[75776];
    // buf b at smem + b*32768: Kr +0, Ki +8192, Vr +16384, Vi +24576
    short (*sP)[16][40] = (short(*)[16][40])(smem + 65536);  // 8 waves, 10KB

    const int tid  = threadIdx.x;
    const int lane = tid & 63, wave = tid >> 6;      // 0..7
    const int quad = lane >> 4, l16 = lane & 15;
    const int sw8  = l16 & 7;
    const int qstrip = wave >> 1;                    // 0..3
    const int khalf  = wave & 1;                     // 0..1
    const int qt = blockIdx.x >> 5;                  // qt-major
    const int bh = blockIdx.x & 31;                  // XCD = bh % 8
    const int b  = bh >> 3, h = bh & 7;
    const size_t base = (size_t)bh * (NSEQ*HD);

    const int rsub = lane >> 3;
    const int colg = (lane & 7) ^ rsub;

    const int cb = cnt[b];
    const int nt = (cb + 63) >> 6;                   // compacted key tiles

    // this wave's staging plane (0:Kr 1:Ki 2:Vr 3:Vi), 4 chunks of 1KB
    const int splane = wave >> 1;
    const short* sgp = (splane == 0) ? Kp_r : (splane == 1) ? Kp_i
                     : (splane == 2) ? Vp_r : Vp_i;
    const int sisV = (splane >= 2);
    const int soff = splane * 8192;

    // ---- Q fragments direct from global (once, out of loop) ----
    const short nk = (short)0x8000;
    const short8 neg = {nk,nk,nk,nk,nk,nk,nk,nk};
    short8 fqr[2], fqi[2], fqrn[2];
    #pragma unroll
    for (int ds = 0; ds < 2; ds++) {
        size_t qo = base + (size_t)(qt*64 + qstrip*16 + l16)*HD + ds*32 + quad*8;
        fqr[ds]  = *(const short8*)&Qp_r[qo];
        fqi[ds]  = *(const short8*)&Qp_i[qo];
        fqrn[ds] = fqr[ds] ^ neg;
    }

    float4v zf = {0.f,0.f,0.f,0.f};
    float4v Or[4], Oi[4];
    float lrow[4];
    #pragma unroll
    for (int t = 0; t < 4; t++) { Or[t] = zf; Oi[t] = zf; }
    #pragma unroll
    for (int r = 0; r < 4; r++) lrow[r] = 0.f;

    const float C2 = 0.18033688f;   // 0.125 * log2(e)

    // ---- prologue: stage tile 0 into buf 0 ----
    if (nt > 0) {
        short* lp = (short*)(smem + soff);
        #pragma unroll
        for (int jj = 0; jj < 4; jj++) {
            int j = (wave & 1)*4 + jj;
            int row = j*8 + rsub;
            const short* g = sisV
                ? sgp + base + (size_t)row*NSEQ + colg*8
                : sgp + base + (size_t)row*HD + colg*8;
            GLOAD16(g, lp + j*512);
        }
    }

    for (int kt = 0; kt < nt; kt++) {
        __syncthreads();    // buf[kt&1] staged (vmcnt drained); prev reads done

        // ---- issue async staging of tile kt+1 into the other buffer ----
        if (kt + 1 < nt) {
            const int kn = (kt + 1) * 64;
            short* lp = (short*)(smem + ((kt + 1) & 1)*32768 + soff);
            #pragma unroll
            for (int jj = 0; jj < 4; jj++) {
                int j = (wave & 1)*4 + jj;
                int row = j*8 + rsub;
                const short* g = sisV
                    ? sgp + base + (size_t)row*NSEQ + kn + colg*8
                    : sgp + base + (size_t)(kn + row)*HD + colg*8;
                GLOAD16(g, lp + j*512);
            }
        }

        // ---- compute from buf[kt&1] ----
        const char* buf = smem + (kt & 1)*32768;
        short (*sK0)[64] = (short(*)[64])(buf);
        short (*sK1)[64] = (short(*)[64])(buf + 8192);
        short (*sV0)[64] = (short(*)[64])(buf + 16384);
        short (*sV1)[64] = (short(*)[64])(buf + 24576);
        const int k0 = kt*64;

        // S = Q conj(K)^T over this wave's 32-key half
        float4v Sr[2], Si[2];
        Sr[0] = zf; Sr[1] = zf; Si[0] = zf; Si[1] = zf;
        __builtin_amdgcn_s_setprio(1);
        #pragma unroll
        for (int t = 0; t < 2; t++)
            #pragma unroll
            for (int ds = 0; ds < 2; ds++) {
                int u = ((ds*4 + quad) ^ sw8) * 8;
                int krow = khalf*32 + t*16 + l16;
                short8 kr = *(short8*)&sK0[krow][u];
                short8 ki = *(short8*)&sK1[krow][u];
                Sr[t] = MFMA16(fqr[ds],  kr, Sr[t]);
                Sr[t] = MFMA16(fqi[ds],  ki, Sr[t]);
                Si[t] = MFMA16(fqi[ds],  kr, Si[t]);
                Si[t] = MFMA16(fqrn[ds], ki, Si[t]);
            }
        __builtin_amdgcn_s_setprio(0);

        // e = exp(|S|/8) (no max shift), per-lane l, P strip.
        // Valid iff compacted key index < cnt[b]; pad V cols are zero.
        #pragma unroll
        for (int t = 0; t < 2; t++) {
            bool mv = (k0 + khalf*32 + t*16 + l16) < cb;
            #pragma unroll
            for (int r = 0; r < 4; r++) {
                float a = Sr[t][r], c = Si[t][r];
                float x = fmaf(a, a, c*c);
                float s = __builtin_amdgcn_sqrtf(x);
                float e = mv ? __builtin_amdgcn_exp2f(C2 * s) : 0.f;
                lrow[r] += e;
                sP[wave][quad*4 + r][t*16 + l16] = f2b(e);
            }
        }

        // O += P @ V over this wave's 32 keys (K=32, one frag)
        {
            short8 fp = *(short8*)&sP[wave][l16][quad*8];
            __builtin_amdgcn_s_setprio(1);
            #pragma unroll
            for (int t = 0; t < 4; t++) {
                int u = ((khalf*4 + quad) ^ sw8) * 8;
                short8 vr = *(short8*)&sV0[t*16 + l16][u];
                short8 vi = *(short8*)&sV1[t*16 + l16][u];
                Or[t] = MFMA16(fp, vr, Or[t]);
                Oi[t] = MFMA16(fp, vi, Oi[t]);
            }
            __builtin_amdgcn_s_setprio(0);
        }
    }

    // ---- combine key-half partners (khalf 1 -> 0) through reused LDS ----
    __syncthreads();                          // all buf/sP reads done
    float* sC = (float*)smem;                 // 32KB O partials
    float* sL = (float*)(smem + 32768);       // 4KB  l partials
    if (khalf == 1) {
        #pragma unroll
        for (int t = 0; t < 4; t++)
            #pragma unroll
            for (int r = 0; r < 4; r++) {
                int o8 = ((qstrip*4 + t)*64 + lane)*8 + r*2;
                sC[o8]     = Or[t][r];
                sC[o8 + 1] = Oi[t][r];
            }
        int lo = (qstrip*64 + lane)*4;
        #pragma unroll
        for (int r = 0; r < 4; r++) sL[lo + r] = lrow[r];
    }
    __syncthreads();
    if (khalf == 0) {
        #pragma unroll
        for (int t = 0; t < 4; t++)
            #pragma unroll
            for (int r = 0; r < 4; r++) {
                int o8 = ((qstrip*4 + t)*64 + lane)*8 + r*2;
                Or[t][r] += sC[o8];
                Oi[t][r] += sC[o8 + 1];
            }
        int lo = (qstrip*64 + lane)*4;
        float inv[4];
        #pragma unroll
        for (int r = 0; r < 4; r++) {
            float ls = lrow[r] + sL[lo + r];
            ls += __shfl_xor(ls, 1, 64);
            ls += __shfl_xor(ls, 2, 64);
            ls += __shfl_xor(ls, 4, 64);
            ls += __shfl_xor(ls, 8, 64);
            inv[r] = (ls > 0.f) ? 1.f/ls : 0.f;
        }
        #pragma unroll
        for (int t = 0; t < 4; t++)
            #pragma unroll
            for (int r = 0; r < 4; r++) {
                int q = qt*64 + qstrip*16 + quad*4 + r;
                int d = t*16 + l16;
                size_t o = ((size_t)(b*NSEQ + q))*NHD + h*HD + d;
                Ar[o] = f2b(Or[t][r] * inv[r]);
                Ai[o] = f2b(Oi[t][r] * inv[r]);
            }
    }
}

// ---------------------------------------------------------------------------
// Output projection, all-bf16, split-N (64x32 tiles). DOUBLE-BUFFERED
// 1-barrier K-loop (K-chunk 64, 48KB LDS). 1D grid 512 with XCD-chunked
// role decode: the 8 n-blocks sharing an A panel land on one XCD.
// Out = A @ (WOr + i WOi)^T; direct fp32 stores.
// ---------------------------------------------------------------------------
__global__ __launch_bounds__(256) void cgemm_out(
    const short* __restrict__ A_r, const short* __restrict__ A_i,
    const short* __restrict__ W_r, const short* __restrict__ W_i,
    float* __restrict__ Out, int writeImagPlane)
{
    __shared__ short sA[2][2][64][64];   // [buf][plane] 32KB
    __shared__ short sW[2][2][32][64];   // [buf][plane] 16KB
    const int tid  = threadIdx.x;
    const int lane = tid & 63, wave = tid >> 6;
    const int quad = lane >> 4, l16 = lane & 15;
    const int sw8  = l16 & 7;
    const int rsub = lane >> 3;
    const int colg = (lane & 7) ^ rsub;

    // XCD-chunked bijective role decode (512 = 8 XCDs * 64 roles)
    const int wgid = blockIdx.x;
    const int flat = (wgid & 7) * 64 + (wgid >> 3);
    const int n0 = (flat & 7) * 32, m0 = (flat >> 3) * 64;

    const short nk = (short)0x8000;
    const short8 neg = {nk,nk,nk,nk,nk,nk,nk,nk};

    float4v zf = {0.f,0.f,0.f,0.f};
    float4v Yr[2], Yi[2];
    #pragma unroll
    for (int t = 0; t < 2; t++) { Yr[t] = zf; Yi[t] = zf; }

    #define OUT_STAGE(kc, bf)                                                 \
        if (wave < 2) {                                                       \
            const short* gp = wave ? A_i : A_r;                               \
            short* lp = &sA[bf][wave][0][0];                                  \
            _Pragma("unroll")                                                 \
            for (int j = 0; j < 8; j++)                                       \
                GLOAD16(gp + (size_t)(m0 + j*8 + rsub)*NHD + (kc) + colg*8,   \
                        lp + j*512);                                          \
        } else {                                                              \
            const short* gp = (wave == 3) ? W_i : W_r;                        \
            short* lp = &sW[bf][wave - 2][0][0];                              \
            _Pragma("unroll")                                                 \
            for (int j = 0; j < 4; j++)                                       \
                GLOAD16(gp + (size_t)(n0 + j*8 + rsub)*NHD + (kc) + colg*8,   \
                        lp + j*512);                                          \
        }

    OUT_STAGE(0, 0);                        // prologue: chunk 0 -> buf 0

    for (int c = 0; c < 8; c++) {           // 8 chunks of K=64 (NHD=512)
        __syncthreads();                    // chunk c staged; buf c&1 free'd
        if (c + 1 < 8) { OUT_STAGE((c + 1)*64, (c + 1) & 1); }
        const int bf = c & 1;

        short8 far[2], fai[2], fain[2];
        #pragma unroll
        for (int ds = 0; ds < 2; ds++) {
            int u = ((ds*4 + quad) ^ sw8) * 8;
            far[ds]  = *(short8*)&sA[bf][0][wave*16 + l16][u];
            fai[ds]  = *(short8*)&sA[bf][1][wave*16 + l16][u];
            fain[ds] = fai[ds] ^ neg;
        }
        #pragma unroll
        for (int t = 0; t < 2; t++)
            #pragma unroll
            for (int ds = 0; ds < 2; ds++) {
                int u = ((ds*4 + quad) ^ sw8) * 8;
                short8 wr = *(short8*)&sW[bf][0][t*16 + l16][u];
                short8 wi = *(short8*)&sW[bf][1][t*16 + l16][u];
                Yr[t] = MFMA16(far[ds],  wr, Yr[t]);
                Yr[t] = MFMA16(fain[ds], wi, Yr[t]);
                Yi[t] = MFMA16(far[ds],  wi, Yi[t]);
                Yi[t] = MFMA16(fai[ds],  wr, Yi[t]);
            }
    }
    #undef OUT_STAGE

    const size_t TOT = (size_t)NBATCH * NSEQ * RD;   // 1,048,576
    #pragma unroll
    for (int t = 0; t < 2; t++)
        #pragma unroll
        for (int r = 0; r < 4; r++) {
            int row = m0 + wave*16 + quad*4 + r;
            int col = n0 + t*16 + l16;
            size_t o = (size_t)row*RD + col;
            Out[o] = Yr[t][r];
            if (writeImagPlane) Out[o + TOT] = Yi[t][r];
        }
}

// ---------------------------------------------------------------------------
extern "C" void kernel_launch(void* const* d_in, const int* in_sizes, int n_in,
                              void* d_out, int out_size, void* d_ws, size_t ws_size,
                              hipStream_t stream)
{
    float* out = (float*)d_out;

    const size_t P = (size_t)NBATCH * NHEAD * NSEQ * HD;   // 2,097,152
    const size_t H = (size_t)NBATCH * NSEQ * RD;           // 1,048,576
    const size_t WSZ = (size_t)NHD * RD;                   // 131,072

    short* bws = (short*)d_ws;
    // bf16 projected planes [0, 24MB)
    short* Qpr = bws + 0*P;  short* Qpi = bws + 1*P;
    short* Kpr = bws + 2*P;  short* Kpi = bws + 3*P;
    short* Vpr = bws + 4*P;  short* Vpi = bws + 5*P;
    // converted-input region @ 24MB (dead after cgemm_proj, except WO)
    short* conv = bws + 6*P;
    short* cX[6]; for (int i = 0; i < 6; i++) cX[i] = conv + i*H;       // 12MB
    short* cW[6]; for (int i = 0; i < 6; i++) cW[i] = conv + 6*H + i*WSZ;
    short* cWOr = conv + 6*H + 6*WSZ;
    short* cWOi = conv + 6*H + 7*WSZ;
    // mask compaction: idx[4][1024] (ushort) + cnt[4] (int)
    unsigned short* midx = (unsigned short*)(conv + 6*H + 8*WSZ);
    int* mcnt = (int*)(midx + 4096);
    // A planes alias the (dead) converted X region
    short* Apr = conv;          // 4MB
    short* Api = conv + P;      // 4MB

    const size_t TOT = (size_t)NBATCH * NSEQ * RD;
    const int writeImagPlane = ((size_t)out_size >= 2*TOT) ? 1 : 0;

    ConvArgs ca;
    for (int i = 0; i < 6; i++) {
        ca.src[i] = (const float*)d_in[i];  ca.dst[i] = cX[i];  ca.n4[i] = (int)(H/4);
    }
    for (int i = 0; i < 6; i++) {
        ca.src[6+i] = (const float*)d_in[6+i]; ca.dst[6+i] = cW[i]; ca.n4[6+i] = (int)(WSZ/4);
    }
    ca.src[12] = (const float*)d_in[12]; ca.dst[12] = cWOr; ca.n4[12] = (int)(WSZ/4);
    ca.src[13] = (const float*)d_in[13]; ca.dst[13] = cWOi; ca.n4[13] = (int)(WSZ/4);
    ca.src[14] = (const float*)d_in[14]; ca.dst[14] = (short*)midx; ca.n4[14] = 0;

    ProjArgs pa;
    pa.Xr[0] = cX[0]; pa.Xi[0] = cX[1];
    pa.Xr[1] = cX[2]; pa.Xi[1] = cX[3];   // gathered in convert
    pa.Xr[2] = cX[4]; pa.Xi[2] = cX[5];   // gathered in convert
    pa.Wr[0] = cW[0]; pa.Wi[0] = cW[1];
    pa.Wr[1] = cW[2]; pa.Wi[1] = cW[3];
    pa.Wr[2] = cW[4]; pa.Wi[2] = cW[5];
    pa.Yr[0] = Qpr; pa.Yi[0] = Qpi;
    pa.Yr[1] = Kpr; pa.Yi[1] = Kpi;
    pa.Yr[2] = Vpr; pa.Yi[2] = Vpi;
    pa.cnt = mcnt;

    convert_bf16<<<dim3(256, 15), 256, 0, stream>>>(ca);
    cgemm_proj<<<dim3(768), 256, 0, stream>>>(pa);
    attn_mfma<<<dim3(512), 512, 0, stream>>>(Qpr, Qpi, Kpr, Kpi, Vpr, Vpi,
                                             mcnt, Apr, Api);
    cgemm_out<<<dim3(512), 256, 0, stream>>>(Apr, Api, cWOr, cWOi, out,
                                             writeImagPlane);
}